// Round 11
// baseline (89.065 us; speedup 1.0000x reference)
//
#include <hip/hip_runtime.h>

// HyperPatchNoPadding:
//   x: [8, 64, 256, 256] f32, s: [8, 4096, 16, 16] f32, out: [8, 64, 256, 256] f32
//   Per patch (b,pi,pj): Y[o][p*16+q] = sum_c W[o][c] * X[c][p*16+q]
// Round 11: R10 geometry (block = (b,h) image row), but x staged via
// __builtin_amdgcn_global_load_lds (64x 1-KB async strips, no VGPR landing ->
// compiler cannot throttle the burst depth). B-frags from linear f32 LDS via
// scalar reads + cvt. Epilogue = R10 (proven).
#define NB 8
#define FH 16
#define FW 16

typedef __bf16 bf16x8 __attribute__((ext_vector_type(8)));
typedef float  f32x4  __attribute__((ext_vector_type(4)));

#define WS_BYTES ((size_t)NB * 256 * 512 * 16)  // 16 MiB

// ---------------------------------------------------------------------------
// K1: pack/transpose s -> ws (proven).  ws[patch][g]: g=(mt*2+kk)*64+gl holds
// W[mt*16+(gl&15)][kk*32+(gl>>4)*8+j]
// ---------------------------------------------------------------------------
__global__ __launch_bounds__(256) void pack_w_kernel(
    const float* __restrict__ s, bf16x8* __restrict__ ws)
{
    __shared__ float lds[16 * 513];
    const int bid = blockIdx.x;              // 0..1023
    const int b   = bid & 7;                 // XCD bits -> b
    const int kk  = (bid >> 3) & 1;
    const int mt  = (bid >> 4) & 3;
    const int pi  = (bid >> 6) & 15;
    const int tid = threadIdx.x;

    #pragma unroll
    for (int pass = 0; pass < 8; ++pass) {
        const int idx   = pass * 256 + tid;
        const int u     = idx >> 2;
        const int pj4   = idx & 3;
        const int row16 = u >> 5;
        const int cc    = u & 31;
        const size_t row = (size_t)b * 4096 + mt * 1024 + row16 * 64 + kk * 32 + cc;
        const float4 v = *reinterpret_cast<const float4*>(
            s + row * 256 + pi * 16 + pj4 * 4);
        lds[(pj4 * 4 + 0) * 513 + cc * 16 + row16] = v.x;
        lds[(pj4 * 4 + 1) * 513 + cc * 16 + row16] = v.y;
        lds[(pj4 * 4 + 2) * 513 + cc * 16 + row16] = v.z;
        lds[(pj4 * 4 + 3) * 513 + cc * 16 + row16] = v.w;
    }
    __syncthreads();

    const int gl     = tid & 63;
    const int row16  = gl & 15;
    const int lanehi = gl >> 4;
    #pragma unroll
    for (int pjblk = 0; pjblk < 4; ++pjblk) {
        const int pj = pjblk * 4 + (tid >> 6);
        bf16x8 e;
        #pragma unroll
        for (int j = 0; j < 8; ++j)
            e[j] = (__bf16)lds[pj * 513 + (lanehi * 8 + j) * 16 + row16];
        ws[((size_t)(b * 256 + pi * 16 + pj)) * 512 + (mt * 2 + kk) * 64 + gl] = e;
    }
}

// ---------------------------------------------------------------------------
// K2: GEMM. Block = (b, h): one image row. 256 thr / 4 waves, 64 KiB LDS.
// phase1: 64 async gload_lds strips -> smemf[c][w] f32 (linear).
// phase2: per wave 4 patches; B-frag = 16 scalar LDS reads + cvt; n = q.
// phase3: out staged in LDS (reuses first 32 KB), 1-KB-row wide stores.
// ---------------------------------------------------------------------------
__global__ __launch_bounds__(256) void gemm_kernel(
    const float* __restrict__ x,
    const bf16x8* __restrict__ ws,
    float* __restrict__ out)
{
    __shared__ float smemf[16384];          // 64 KiB
    const int bid = blockIdx.x;             // 0..2047
    const int b   = bid & 7;                // XCD bits -> b
    const int h   = bid >> 3;               // image row 0..255
    const int pi  = h >> 4;
    const int t   = threadIdx.x;            // 0..255
    const int lane = t & 63;
    const int wv   = t >> 6;                // 0..3
    const int q    = lane & 15;
    const int hi   = lane >> 4;

    // ---- phase 1: async-stage x row h (64 c-planes x 1 KB) into LDS ----
    {
        const float* xrow = x + (size_t)b * 64 * 65536 + (size_t)h * 256 + lane * 4;
        #pragma unroll
        for (int k = 0; k < 16; ++k) {
            const int c = wv * 16 + k;      // wave-uniform strip id
            __builtin_amdgcn_global_load_lds(
                (const __attribute__((address_space(1))) void*)(xrow + (size_t)c * 65536),
                (__attribute__((address_space(3))) void*)(&smemf[c * 256]),
                16, 0, 0);
        }
    }
    asm volatile("s_waitcnt vmcnt(0)" ::: "memory");
    __syncthreads();

    // ---- phase 2: 4 patches per wave; MFMA n=q ----
    f32x4 acc[4][4];                        // [j][mt]
    #pragma unroll
    for (int j = 0; j < 4; ++j) {
        const int pj = wv * 4 + j;
        const int w  = pj * 16 + q;
        const bf16x8* wbase = ws + ((size_t)(b * 256 + pi * 16 + pj)) * 512;
        bf16x8 bf[2];
        #pragma unroll
        for (int kk = 0; kk < 2; ++kk) {
            bf16x8 e;
            #pragma unroll
            for (int jj = 0; jj < 8; ++jj) {
                const int c = kk * 32 + hi * 8 + jj;
                e[jj] = (__bf16)smemf[c * 256 + w];
            }
            bf[kk] = e;
        }
        #pragma unroll
        for (int mt = 0; mt < 4; ++mt) {
            acc[j][mt] = (f32x4){0.f, 0.f, 0.f, 0.f};
            acc[j][mt] = __builtin_amdgcn_mfma_f32_16x16x32_bf16(
                wbase[(mt * 2 + 0) * 64 + lane], bf[0], acc[j][mt], 0, 0, 0);
            acc[j][mt] = __builtin_amdgcn_mfma_f32_16x16x32_bf16(
                wbase[(mt * 2 + 1) * 64 + lane], bf[1], acc[j][mt], 0, 0, 0);
        }
    }
    __syncthreads();                        // x-LDS dead; reuse for out staging

    // ---- phase 3: out in two o-halves of 32 planes (R10 proven) ----
    #pragma unroll
    for (int h2 = 0; h2 < 2; ++h2) {
        #pragma unroll
        for (int j = 0; j < 4; ++j) {
            const int w = (wv * 4 + j) * 16 + q;
            #pragma unroll
            for (int m2 = 0; m2 < 2; ++m2) {
                const int mt = h2 * 2 + m2;
                #pragma unroll
                for (int r = 0; r < 4; ++r) {
                    const int o2 = m2 * 16 + hi * 4 + r;
                    smemf[o2 * 256 + (w ^ ((o2 & 7) << 2))] = acc[j][mt][r];
                }
            }
        }
        __syncthreads();

        #pragma unroll
        for (int ps = 0; ps < 8; ++ps) {
            const int o2 = ps * 4 + wv;
            f32x4 vv = *(const f32x4*)&smemf[o2 * 256
                                             + ((lane * 4) ^ ((o2 & 7) << 2))];
            *(f32x4*)(out + (size_t)(b * 64 + h2 * 32 + o2) * 65536
                          + (size_t)h * 256 + lane * 4) = vv;
        }
        if (h2 == 0) __syncthreads();
    }
}

// ---------------------------------------------------------------------------
// Fallback (round-2 single kernel, proven) if ws is too small.
// ---------------------------------------------------------------------------
__global__ __launch_bounds__(512) void hyperpatch_fallback(
    const float* __restrict__ x,
    const float* __restrict__ s,
    float* __restrict__ out)
{
    __shared__ bf16x8 afrag[2][512];
    const int bid = blockIdx.x;
    const int b   = bid >> 7;
    const int pi  = (bid >> 3) & 15;
    const int pj0 = (bid & 7) * 2;
    const int t   = threadIdx.x;
    const int lane = t & 63;
    const int wv   = t >> 6;

    {
        const int g  = t;
        const int mt = g >> 7;
        const int kk = (g >> 6) & 1;
        const int gl = g & 63;
        const int o  = mt * 16 + (gl & 15);
        const int c0 = kk * 32 + (gl >> 4) * 8;
        const float2* sb2 = reinterpret_cast<const float2*>(
            s + ((size_t)b * 4096) * 256 + pi * 16 + pj0);
        bf16x8 ta, tb;
        #pragma unroll
        for (int j = 0; j < 8; ++j) {
            float2 v = sb2[(size_t)(o * 64 + c0 + j) * 128];
            ta[j] = (__bf16)v.x;
            tb[j] = (__bf16)v.y;
        }
        afrag[0][g] = ta;
        afrag[1][g] = tb;
    }

    const int pat  = wv >> 2;
    const int wrow = wv & 3;
    const int q  = lane & 15;
    const int cb = (lane >> 4) * 8;
    const float* xbase = x + (((size_t)b * 64) * 256 + pi * 16) * 256
                           + (pj0 + pat) * 16 + q;
    bf16x8 bfrag[4][2];
    #pragma unroll
    for (int nt = 0; nt < 4; ++nt) {
        const int p = wrow * 4 + nt;
        #pragma unroll
        for (int kk = 0; kk < 2; ++kk) {
            const int c = kk * 32 + cb;
            bf16x8 tv;
            #pragma unroll
            for (int j = 0; j < 8; ++j) {
                float v = xbase[(size_t)(c + j) * 65536 + (size_t)p * 256];
                tv[j] = (__bf16)v;
            }
            bfrag[nt][kk] = tv;
        }
    }

    __syncthreads();

    bf16x8 a[4][2];
    #pragma unroll
    for (int mt = 0; mt < 4; ++mt)
        #pragma unroll
        for (int kk = 0; kk < 2; ++kk)
            a[mt][kk] = afrag[pat][(mt * 2 + kk) * 64 + lane];

    f32x4 acc[4][4];
    #pragma unroll
    for (int mt = 0; mt < 4; ++mt)
        #pragma unroll
        for (int nt = 0; nt < 4; ++nt)
            acc[mt][nt] = (f32x4){0.f, 0.f, 0.f, 0.f};

    #pragma unroll
    for (int mt = 0; mt < 4; ++mt) {
        #pragma unroll
        for (int nt = 0; nt < 4; ++nt) {
            acc[mt][nt] = __builtin_amdgcn_mfma_f32_16x16x32_bf16(
                a[mt][0], bfrag[nt][0], acc[mt][nt], 0, 0, 0);
            acc[mt][nt] = __builtin_amdgcn_mfma_f32_16x16x32_bf16(
                a[mt][1], bfrag[nt][1], acc[mt][nt], 0, 0, 0);
        }
    }

    const int ro = (lane >> 4) * 4;
    float* obase = out + (((size_t)b * 64) * 256 + pi * 16) * 256
                       + (pj0 + pat) * 16 + q;
    #pragma unroll
    for (int mt = 0; mt < 4; ++mt) {
        #pragma unroll
        for (int nt = 0; nt < 4; ++nt) {
            const int p = wrow * 4 + nt;
            #pragma unroll
            for (int r = 0; r < 4; ++r) {
                const int o = mt * 16 + ro + r;
                obase[(size_t)o * 65536 + (size_t)p * 256] = acc[mt][nt][r];
            }
        }
    }
}

extern "C" void kernel_launch(void* const* d_in, const int* in_sizes, int n_in,
                              void* d_out, int out_size, void* d_ws, size_t ws_size,
                              hipStream_t stream)
{
    (void)in_sizes; (void)n_in; (void)out_size;
    const float* x = (const float*)d_in[0];
    const float* s = (const float*)d_in[1];
    float* out = (float*)d_out;

    if (ws_size >= WS_BYTES && d_ws != nullptr) {
        bf16x8* ws = (bf16x8*)d_ws;
        pack_w_kernel<<<dim3(1024), dim3(256), 0, stream>>>(s, ws);
        gemm_kernel<<<dim3(2048), dim3(256), 0, stream>>>(x, ws, out);
    } else {
        hyperpatch_fallback<<<dim3(NB * FH * (FW / 2)), dim3(512), 0, stream>>>(x, s, out);
    }
}

// Round 12
// 77.589 us; speedup vs baseline: 1.1479x; 1.1479x over previous
//
#include <hip/hip_runtime.h>

// HyperPatchNoPadding:
//   x: [8, 64, 256, 256] f32, s: [8, 4096, 16, 16] f32, out: [8, 64, 256, 256] f32
//   Per patch (b,pi,pj): Y[o][p*16+q] = sum_c W[o][c] * X[c][p*16+q]
// Round 12: single FUSED kernel. Block = (b, pjp, pi) = 2 patches x 16 h-rows,
// looped as 4 tiles of 4 p-rows with a software pipeline (prefetch next tile
// to regs during MFMA/epilogue). W gathered once per block into LDS frags;
// A-frags in registers for the whole block. No workspace, no pack kernel.
#define NB 8

typedef __bf16 bf16x8 __attribute__((ext_vector_type(8)));
typedef float  f32x4  __attribute__((ext_vector_type(4)));

__global__ __launch_bounds__(256) void fused_kernel(
    const float* __restrict__ x,
    const float* __restrict__ s,
    float* __restrict__ out)
{
    // LDS: [0,16K) W-frags (pat0 8K, pat1 8K); [16K,32K) xbuf0; [32K,48K) xbuf1
    __shared__ char smem[49152];

    const int bid = blockIdx.x;            // 0..1023
    const int b   = bid & 7;               // XCD bits -> b
    const int pjp = (bid >> 3) & 7;        // siblings adjacent (L2 reuse of s)
    const int pi  = bid >> 6;              // 0..15
    const int t   = threadIdx.x;           // 0..255
    const int lane = t & 63;
    const int wv   = t >> 6;               // 0..3
    const int q    = lane & 15;
    const int hi   = lane >> 4;
    const int pat  = wv & 1;               // patch within pair
    const int pgrp = wv >> 1;              // p-pair group (p = pgrp*2+pp)
    const int w0   = pjp * 32;             // global w base (floats)
    const int pj0  = pjp * 2;

    // staging thread map (all 256 threads): p' = t>>6, w-quad = (t>>3)&7, c-octet = t&7
    const int sp_p = t >> 6;
    const int swq  = (t >> 3) & 7;
    const int sco  = t & 7;
    const float* xbase = x + (size_t)b * 4194304 + (size_t)(sco * 8) * 65536
                           + w0 + swq * 4;

    // ---- W gather -> LDS fragments, both patches (once per block) ----
    // row r = o*64+c of s[b]; frag entry g=(mt*2+kk)*64 + ((c>>3)&3)*16 + (o&15),
    // bf16 j=c&7. Scattered 8-B loads, L2-shared by the 8 pjp-sibling blocks.
    {
        const float2* sp2 = (const float2*)(s + (size_t)b * 1048576 + pi * 16 + pj0);
        #pragma unroll
        for (int k = 0; k < 16; ++k) {
            const int r = t + k * 256;     // 0..4095
            float2 v = sp2[(size_t)r * 128];
            const int o = r >> 6, c = r & 63;
            const int ent = ((o >> 4) * 2 + (c >> 5)) * 64 + ((c >> 3) & 3) * 16 + (o & 15);
            const int byt = ent * 16 + (c & 7) * 2;
            *(__bf16*)(smem + byt)        = (__bf16)v.x;   // patch pat=0
            *(__bf16*)(smem + 8192 + byt) = (__bf16)v.y;   // patch pat=1
        }
    }

    // ---- stage x tile 0 into xbuf0 ----
    {
        const int row0 = pi * 16;
        f32x4 v[8];
        #pragma unroll
        for (int cc = 0; cc < 8; ++cc)
            v[cc] = *(const f32x4*)(xbase + (size_t)cc * 65536
                                    + (size_t)(row0 + sp_p) * 256);
        #pragma unroll
        for (int i = 0; i < 4; ++i) {
            const int w = swq * 4 + i;
            bf16x8 e;
            #pragma unroll
            for (int cc = 0; cc < 8; ++cc) e[cc] = (__bf16)v[cc][i];
            *(bf16x8*)(smem + 16384 + sp_p * 4096 + w * 128
                       + ((sco * 16) ^ ((w & 7) << 4) ^ (sp_p << 4))) = e;
        }
    }
    __syncthreads();

    // ---- A fragments: registers for the whole block ----
    bf16x8 a[4][2];
    #pragma unroll
    for (int mt = 0; mt < 4; ++mt)
        #pragma unroll
        for (int kk = 0; kk < 2; ++kk)
            a[mt][kk] = *(const bf16x8*)(smem + pat * 8192
                          + ((mt * 2 + kk) * 64 + lane) * 16);

    int cur = 0;
    #pragma unroll
    for (int tile = 0; tile < 4; ++tile) {
        const int row0 = pi * 16 + tile * 4;
        char* bufc = smem + 16384 + cur * 16384;

        // (1) prefetch next tile's x into registers (issue-early)
        f32x4 nv[8];
        if (tile < 3) {
            #pragma unroll
            for (int cc = 0; cc < 8; ++cc)
                nv[cc] = *(const f32x4*)(xbase + (size_t)cc * 65536
                                         + (size_t)(row0 + 4 + sp_p) * 256);
        }
        __builtin_amdgcn_sched_barrier(0);

        // (2) B fragments from current buffer
        bf16x8 bf[2][2];
        #pragma unroll
        for (int pp = 0; pp < 2; ++pp) {
            const int p = pgrp * 2 + pp;
            const int w = pat * 16 + q;
            #pragma unroll
            for (int kk = 0; kk < 2; ++kk) {
                const int co = kk * 4 + hi;
                bf[pp][kk] = *(const bf16x8*)(bufc + p * 4096 + w * 128
                              + ((co * 16) ^ ((w & 7) << 4) ^ (p << 4)));
            }
        }

        // (3) MFMA
        f32x4 acc[2][4];
        #pragma unroll
        for (int pp = 0; pp < 2; ++pp)
            #pragma unroll
            for (int mt = 0; mt < 4; ++mt) {
                acc[pp][mt] = (f32x4){0.f, 0.f, 0.f, 0.f};
                acc[pp][mt] = __builtin_amdgcn_mfma_f32_16x16x32_bf16(
                    a[mt][0], bf[pp][0], acc[pp][mt], 0, 0, 0);
                acc[pp][mt] = __builtin_amdgcn_mfma_f32_16x16x32_bf16(
                    a[mt][1], bf[pp][1], acc[pp][mt], 0, 0, 0);
            }

        // (4) write-late: cvt + ds_write next tile into the other buffer
        if (tile < 3) {
            char* bufn = smem + 16384 + (cur ^ 1) * 16384;
            #pragma unroll
            for (int i = 0; i < 4; ++i) {
                const int w = swq * 4 + i;
                bf16x8 e;
                #pragma unroll
                for (int cc = 0; cc < 8; ++cc) e[cc] = (__bf16)nv[cc][i];
                *(bf16x8*)(bufn + sp_p * 4096 + w * 128
                           + ((sco * 16) ^ ((w & 7) << 4) ^ (sp_p << 4))) = e;
            }
        }
        __syncthreads();                   // bufc free for epilogue staging

        // (5) epilogue: two o-halves staged in bufc (f32), wide stores
        float* ef = (float*)bufc;
        #pragma unroll
        for (int h2 = 0; h2 < 2; ++h2) {
            #pragma unroll
            for (int pp = 0; pp < 2; ++pp) {
                const int p = pgrp * 2 + pp;
                const int w = pat * 16 + q;
                #pragma unroll
                for (int m2 = 0; m2 < 2; ++m2) {
                    const int mt = h2 * 2 + m2;
                    #pragma unroll
                    for (int r = 0; r < 4; ++r) {
                        const int o2 = m2 * 16 + hi * 4 + r;
                        ef[(o2 * 4 + p) * 32 + (w ^ ((o2 & 7) << 2))] = acc[pp][mt][r];
                    }
                }
            }
            __syncthreads();
            #pragma unroll
            for (int ps = 0; ps < 4; ++ps) {
                const int line = ps * 32 + (t >> 3);   // 0..127
                const int o2 = line >> 2, p = line & 3;
                f32x4 vv = *(const f32x4*)&ef[(o2 * 4 + p) * 32
                                              + ((sco * 4) ^ ((o2 & 7) << 2))];
                *(f32x4*)(out + (size_t)(b * 64 + h2 * 32 + o2) * 65536
                              + (size_t)(row0 + p) * 256 + w0 + sco * 4) = vv;
            }
            __syncthreads();               // ef reusable (half1 / next tile)
        }
        cur ^= 1;
    }
}

extern "C" void kernel_launch(void* const* d_in, const int* in_sizes, int n_in,
                              void* d_out, int out_size, void* d_ws, size_t ws_size,
                              hipStream_t stream)
{
    (void)in_sizes; (void)n_in; (void)out_size; (void)d_ws; (void)ws_size;
    const float* x = (const float*)d_in[0];
    const float* s = (const float*)d_in[1];
    float* out = (float*)d_out;

    fused_kernel<<<dim3(1024), dim3(256), 0, stream>>>(x, s, out);
}